// Round 17
// baseline (1134.462 us; speedup 1.0000x reference)
//
#include <hip/hip_runtime.h>

#define S 128
#define NEGF (-1e30f)
#define MAXB 16
#define NT 1024
#define STAGE_SZ 8064     // max over wn of 2*(S-wn-1)*((wn-1)|1)  (wn=63)
#define PKB 700000        // per-batch packed sib floats (>= 698250 exact)
#define RL2 1.4426950408889634f   // 1/ln2 : scores -> exp2 domain
#define LN2 0.6931471805599453f

// Static device workspace (d_ws proved unreliable in rounds 0-2).
__device__ float g_ssw[MAXB * S * S];        // sibling spans (exp2 domain)
__device__ float g_spk[(size_t)MAXB * PKB];  // packed sib * RL2
__device__ float g_logZ[2 * MAXB];           // [0,MAXB): real; rest: ablation dummy
__device__ float g_partials[512];

__device__ __forceinline__ bool mask_at(const unsigned char* m, int i, bool by) {
  return by ? (m[i] != 0) : (((const int*)m)[i] != 0);
}

// global -> LDS DMA, 4B/lane (r6-r16 verified).
__device__ __forceinline__ void gload_lds4(const float* g, float* l) {
  __builtin_amdgcn_global_load_lds(
      (const __attribute__((address_space(1))) unsigned int*)g,
      (__attribute__((address_space(3))) unsigned int*)l, 4, 0, 0);
}

// Online-lse pieces in EXP2 DOMAIN: inputs pre-scaled by 1/ln2, so exp2f/log2f
// compile to bare v_exp_f32/v_log_f32 (no mul). Finite NEGF sentinel => no NaN.
__device__ __forceinline__ void upd(float& m, float& s, float v) {
  float mn = fmaxf(m, v);
  s = s * exp2f(m - mn) + exp2f(v - mn);
  m = mn;
}
__device__ __forceinline__ void fold(float& m0, float& s0, float m1, float s1) {
  float mn = fmaxf(m0, m1);
  s0 = s0 * exp2f(m0 - mn) + s1 * exp2f(m1 - mn);
  m0 = mn;
}
template <int CTRL>
__device__ __forceinline__ float dpp_f(float x) {
  int i = __float_as_int(x);
  return __int_as_float(__builtin_amdgcn_update_dpp(i, i, CTRL, 0xF, 0xF, false));
}
// Cross-lane (m,s) fold over p=2^lp lane-aligned groups (r5-r16 verified).
__device__ __forceinline__ void xfold(float& m, float& s, int lp) {
  if (lp >= 1) { float mo = dpp_f<0xB1>(m),  so = dpp_f<0xB1>(s);  fold(m, s, mo, so); }
  if (lp >= 2) { float mo = dpp_f<0x4E>(m),  so = dpp_f<0x4E>(s);  fold(m, s, mo, so); }
  if (lp >= 3) { float mo = dpp_f<0x141>(m), so = dpp_f<0x141>(s); fold(m, s, mo, so); }
  if (lp >= 4) { float mo = dpp_f<0x140>(m), so = dpp_f<0x140>(s); fold(m, s, mo, so); }
}
__device__ __forceinline__ int lp_cap(int cap) {
  return cap >= 16 ? 4 : cap >= 8 ? 3 : cap >= 4 ? 2 : cap >= 2 ? 1 : 0;
}

// Chunk-8 accumulate, compile-time strides, exp2 domain (r12-r16 math shape).
template <int SA, int SB>
__device__ __forceinline__ void acc2(const float* a, const float* b,
                                     int n, float& M, float& Ss) {
  int i = 0;
  for (; i + 8 <= n; i += 8) {
    float v0 = a[0 * SA] + b[0 * SB];
    float v1 = a[1 * SA] + b[1 * SB];
    float v2 = a[2 * SA] + b[2 * SB];
    float v3 = a[3 * SA] + b[3 * SB];
    float v4 = a[4 * SA] + b[4 * SB];
    float v5 = a[5 * SA] + b[5 * SB];
    float v6 = a[6 * SA] + b[6 * SB];
    float v7 = a[7 * SA] + b[7 * SB];
    float mc = fmaxf(fmaxf(fmaxf(v0, v1), fmaxf(v2, v3)),
                     fmaxf(fmaxf(v4, v5), fmaxf(v6, v7)));
    float s8 = ((exp2f(v0 - mc) + exp2f(v1 - mc)) +
                (exp2f(v2 - mc) + exp2f(v3 - mc))) +
               ((exp2f(v4 - mc) + exp2f(v5 - mc)) +
                (exp2f(v6 - mc) + exp2f(v7 - mc)));
    float mn = fmaxf(M, mc);
    Ss = Ss * exp2f(M - mn) + s8 * exp2f(mc - mn);
    M = mn;
    a += 8 * SA; b += 8 * SB;
  }
  for (; i < n; ++i) { upd(M, Ss, a[0] + b[0]); a += SA; b += SB; }
}
// 3-stream variant (partial: si LDS + ssw global + stage LDS).
template <int SA, int SB, int SC_>
__device__ __forceinline__ void acc3(const float* a, const float* b,
                                     const float* c, int n, float& M, float& Ss) {
  int i = 0;
  for (; i + 8 <= n; i += 8) {
    float v0 = a[0 * SA] + b[0 * SB] + c[0 * SC_];
    float v1 = a[1 * SA] + b[1 * SB] + c[1 * SC_];
    float v2 = a[2 * SA] + b[2 * SB] + c[2 * SC_];
    float v3 = a[3 * SA] + b[3 * SB] + c[3 * SC_];
    float v4 = a[4 * SA] + b[4 * SB] + c[4 * SC_];
    float v5 = a[5 * SA] + b[5 * SB] + c[5 * SC_];
    float v6 = a[6 * SA] + b[6 * SB] + c[6 * SC_];
    float v7 = a[7 * SA] + b[7 * SB] + c[7 * SC_];
    float mc = fmaxf(fmaxf(fmaxf(v0, v1), fmaxf(v2, v3)),
                     fmaxf(fmaxf(v4, v5), fmaxf(v6, v7)));
    float s8 = ((exp2f(v0 - mc) + exp2f(v1 - mc)) +
                (exp2f(v2 - mc) + exp2f(v3 - mc))) +
               ((exp2f(v4 - mc) + exp2f(v5 - mc)) +
                (exp2f(v6 - mc) + exp2f(v7 - mc)));
    float mn = fmaxf(M, mc);
    Ss = Ss * exp2f(M - mn) + s8 * exp2f(mc - mn);
    M = mn;
    a += 8 * SA; b += 8 * SB; c += 8 * SC_;
  }
  for (; i < n; ++i) { upd(M, Ss, a[0] + b[0] + c[0]); a += SA; b += SB; c += SC_; }
}

// One-time repack of s_sib (scaled into exp2 domain) into stage layout.
__global__ __launch_bounds__(256) void pack_kernel(const float* __restrict__ sib) {
  const int wn = 2 + (blockIdx.x % 126);
  const int b = blockIdx.x / 126;
  const int nk2 = S - wn;
  const int rows1 = nk2 - 1;
  if (rows1 <= 0) return;
  const int rowlen = wn - 1;
  const int rlP = rowlen | 1;
  int off = 0;
  for (int v = 2; v < wn; ++v) off += 2 * (S - v - 1) * ((v - 1) | 1);
  const float* SBraw = sib + (size_t)b * S * S * S;   // [dep][head][sib]
  float* dst = g_spk + (size_t)b * PKB + off;
  const int lane5 = threadIdx.x & 31;
  const int R = 2 * rows1;
  for (int r = (threadIdx.x >> 5); r < R; r += 8) {
    const int typ = (r >= rows1) ? 1 : 0;
    const int kr = (r - typ * rows1) + 1;
    const int kw2 = kr + wn;
    const size_t srcoff = (typ == 0)
        ? ((size_t)(kw2 * S + kr) * S + (kr + 1))
        : ((size_t)(kr * S + kw2) * S + (kr + 1));
    const float* src = SBraw + srcoff;
    float* d = dst + r * rlP;
    for (int i = lane5; i < rowlen; i += 32) d[i] = src[i] * RL2;
  }
}

// r15/r16 schedule. ABL==0: full, real logZ. ABL==2: cl/cr reduction loops
// stubbed (writes kept, live-derived garbage values; no data-dependent control
// flow -> timing representative). Dummy logZ slot for ABL!=0.
template <int ABL>
__global__ __launch_bounds__(NT) void dp_kernel(
    const float* __restrict__ arc,          // [B,S,S] s_arc[b,dep,head]
    const unsigned char* __restrict__ mask) // [B,S]
{
  __shared__ float si[S][S];
  __shared__ float sc[S][S];
  __shared__ float stage[STAGE_SZ];
  __shared__ int len_sh, cnt0_sh;

  const int b = blockIdx.x;
  const int tid = threadIdx.x;
  const float* arc_b = arc + (size_t)b * S * S;      // arc_b[dep*S+head]
  const float* spk_b = g_spk + (size_t)b * PKB;
  float* ssw = g_ssw + (size_t)b * S * S;
  float* logZ_out = g_logZ + (ABL ? MAXB : 0);

  if (tid == 0) { len_sh = 0; cnt0_sh = 0; }
  __syncthreads();
  if (tid < S && mask[tid] != 0) atomicAdd(&cnt0_sh, 1);  // byte-interp of row 0
  for (int i = tid; i < S * S; i += NT) {
    (&si[0][0])[i] = NEGF;
    (&sc[0][0])[i] = NEGF;
  }
  __syncthreads();
  const bool bytes = (cnt0_sh >= 64);
  if (tid < S) {
    sc[tid][tid] = 0.0f;               // width-0 complete spans
    if (mask_at(mask, b * S + tid, bytes)) atomicAdd(&len_sh, 1);
  }
  __syncthreads();
  const int len = min(len_sh, S - 1);
  if (tid == 0) logZ_out[b] = 0.0f;    // len==0 fallback

  // Pipeline registers (tid >= 512 only).
  float mP = NEGF, sP = 0.f, arcvP = 0.f;
  if (tid >= 512) {                    // prologue for w=1 finish
    const int fam = (tid >= 768);
    const int floc = tid & 255;
    const int lp = lp_cap(256 / (S - 1));
    const int k = floc >> lp;
    if (k < S - 1)
      arcvP = (fam ? arc_b[k * S + (k + 1)] : arc_b[(k + 1) * S + k]) * RL2;
  }

  int spk_off = 0;

  for (int w = 1; w < S; ++w) {
    const int nk = S - w;
    const int wn = w + 1;

    // ===== issue DMA(w+1) =====
    if (wn < S) {
      const int rows1n = S - wn - 1;
      const int T = 2 * rows1n * ((wn - 1) | 1);
      const float* src = spk_b + spk_off;
      const int wv = tid >> 6, l = tid & 63;
      for (int c = wv; c * 64 < T; c += 16) {
        const int e = c * 64 + l;
        if (e < T) gload_lds4(src + e, &stage[c * 64]);
      }
      spk_off += T;
    }

    // ========== PH_A: slr(w) || finish ir/il(w) ==========
    if (tid < 512) {                   // slr: S(k, k+w), k in [1, nk)
      const int lp = lp_cap(512 / nk);
      const int p = 1 << lp;
      const int q = tid & (p - 1);
      const int k = tid >> lp;
      if (k >= 1 && k < nk) {
        const int kw = k + w;
        const int ch = w >> lp;
        const int i0 = q * ch;
        const int n = ((q == p - 1) ? w : i0 + ch) - i0;
        float M = NEGF, Ss = 0.f;
        acc2<1, 1>(&sc[k][k] + i0, &sc[kw][k + 1] + i0, n, M, Ss);
        xfold(M, Ss, lp);
        if (q == 0) ssw[w * S + k] = log2f(Ss) + M;
      }
    } else {                           // finish ir/il(w) from (mP, sP)
      const int fam = (tid >= 768);
      const int floc = tid & 255;
      const int lp = lp_cap(256 / nk);
      const int p = 1 << lp;
      const int q = floc & (p - 1);
      const int k = floc >> lp;
      if (k < nk) {
        const int kw = k + w;
        float bm;
        if (fam == 0) bm = sc[k][k] + sc[kw][k + 1];
        else bm = (k == 0) ? 0.0f : (sc[kw][kw] + sc[k][kw - 1]);
        float m = mP, s = sP;
        if (q == 0) fold(m, s, bm, 1.0f);
        xfold(m, s, lp);
        if (q == 0) {
          const float r = log2f(s) + m + arcvP;
          if (fam == 0) si[k][kw] = r;
          else          si[kw][k] = r;
        }
      }
    }
    __syncthreads();   // B1: si(w)/ssw(w) final; DMA(w+1) landed

    // ========== PH_B: cl || cr || partial-ir(w+1) || partial-il(w+1) ======
    if (tid < 512) {
      const int fam = (tid >= 256);    // 0 = cl, 1 = cr
      const int floc = tid & 255;
      const int lp = lp_cap(256 / nk);
      const int p = 1 << lp;
      const int q = floc & (p - 1);
      const int k = floc >> lp;
      if (k < nk) {
        const int kw = k + w;
        if constexpr (ABL != 2) {
          const int ch = w >> lp;
          const int i0 = q * ch;
          const int n = ((q == p - 1) ? w : i0 + ch) - i0;
          float M = NEGF, Ss = 0.f;
          if (fam == 0) {      // cl: C(kw->k) over x: sc[k+x][k]+si[kw][k+x]
            acc2<S, 1>(&sc[k + i0][k], &si[kw][k] + i0, n, M, Ss);
            xfold(M, Ss, lp);
            if (q == 0) sc[kw][k] = log2f(Ss) + M;
          } else {             // cr: C(k->kw) over y: si[k][k+y]+sc[k+y][kw]
            acc2<1, S>(&si[k][k + 1] + i0, &sc[k + 1 + i0][kw], n, M, Ss);
            xfold(M, Ss, lp);
            if (q == 0) {
              const float r = log2f(Ss) + M;
              if (k == 0) {
                if (w == len) logZ_out[b] = r * LN2;   // logZ back to nats
                sc[0][w] = (w == len) ? r : NEGF;
              } else {
                sc[k][kw] = r;
              }
            }
          }
        } else {
          // ABL==2 stub: keep writes with live-derived values, drop the loops.
          if (fam == 0) {
            if (q == 0) sc[kw][k] = si[kw][k];
          } else {
            const float r = si[k][k + 1];
            if (q == 0) {
              if (k == 0) {
                if (w == len) logZ_out[b] = r * LN2;
                sc[0][w] = (w == len) ? r : NEGF;
              } else {
                sc[k][kw] = r;
              }
            }
          }
        }
      }
    } else {
      // partial sibling-lse for ir/il(w+1); reads si(<=w), ssw(<=w), stage.
      mP = NEGF; sP = 0.f; arcvP = 0.f;
      if (wn < S) {
        const int fam = (tid >= 768);
        const int floc = tid & 255;
        const int nk2 = S - wn;
        const int lp = lp_cap(256 / nk2);
        const int p = 1 << lp;
        const int q = floc & (p - 1);
        const int k = floc >> lp;
        if (k < nk2) {
          const int kw2 = k + wn;
          arcvP = ((fam == 0) ? arc_b[kw2 * S + k] : arc_b[k * S + kw2]) * RL2;
          if (k >= 1) {
            const int n1n = wn - 1;
            const int rlPn = n1n | 1;
            const int ch = n1n >> lp;
            const int i0 = q * ch;
            const int n = ((q == p - 1) ? n1n : i0 + ch) - i0;
            if (fam == 0) {
              acc3<1, 1 - S, 1>(&si[k][k + 1] + i0,
                                ssw + (wn - 1) * S + (k + 1) + i0 * (1 - S),
                                &stage[(k - 1) * rlPn] + i0, n, mP, sP);
            } else {
              acc3<1, S, 1>(&si[kw2][k + 1] + i0,
                            ssw + S + k + i0 * S,
                            &stage[((nk2 - 1) + (k - 1)) * rlPn] + i0, n, mP, sP);
            }
          }
        }
      }
    }
    __syncthreads();   // B2: sc(w) final
  }
}

// Gather score (raw domain): masked arc + positive-sibling scores, mask count.
__global__ __launch_bounds__(256) void score_kernel(
    const float* __restrict__ arc, const float* __restrict__ sib,
    const unsigned char* __restrict__ mask, const int* __restrict__ arcs,
    const int* __restrict__ sibs, int B)
{
  __shared__ bool bytes_sh;
  if (threadIdx.x == 0) {
    int c = 0;
    for (int i = 0; i < S; ++i) c += (mask[i] != 0);
    bytes_sh = (c >= 64);
  }
  __syncthreads();
  const bool bytes = bytes_sh;

  const int total = B * S * S;
  int tid = blockIdx.x * blockDim.x + threadIdx.x;
  float sum = 0.f, cnt = 0.f;
  for (int e = tid; e < total; e += gridDim.x * blockDim.x) {
    int sv = sibs[e];
    if (sv > 0) sum += sib[(size_t)e * S + sv];
    if ((e & (S - 1)) == 0) {
      int bi = e >> 7;
      if (mask_at(mask, bi, bytes)) { sum += arc[(size_t)bi * S + arcs[bi]]; cnt += 1.f; }
    }
  }
  __shared__ float rs[256], rc[256];
  rs[threadIdx.x] = sum; rc[threadIdx.x] = cnt;
  __syncthreads();
  for (int off = 128; off; off >>= 1) {
    if (threadIdx.x < off) {
      rs[threadIdx.x] += rs[threadIdx.x + off];
      rc[threadIdx.x] += rc[threadIdx.x + off];
    }
    __syncthreads();
  }
  if (threadIdx.x == 0) {
    g_partials[blockIdx.x * 2]     = rs[0];
    g_partials[blockIdx.x * 2 + 1] = rc[0];
  }
}

__global__ __launch_bounds__(256) void final_kernel(int B, float* __restrict__ out)
{
  __shared__ float rs[256], rc[256];
  int t = threadIdx.x;
  float v = -g_partials[t * 2];
  float c = g_partials[t * 2 + 1];
  if (t < B) v += g_logZ[t];
  rs[t] = v; rc[t] = c;
  __syncthreads();
  for (int off = 128; off; off >>= 1) {
    if (t < off) { rs[t] += rs[t + off]; rc[t] += rc[t + off]; }
    __syncthreads();
  }
  if (t == 0) out[0] = rs[0] / rc[0];   // (logZ - score) / mask.sum()
}

extern "C" void kernel_launch(void* const* d_in, const int* in_sizes, int n_in,
                              void* d_out, int out_size, void* d_ws, size_t ws_size,
                              hipStream_t stream) {
  const float* s_arc = (const float*)d_in[0];
  const float* s_sib = (const float*)d_in[1];
  const unsigned char* mask = (const unsigned char*)d_in[2];
  const int* arcs = (const int*)d_in[3];
  const int* sibs = (const int*)d_in[4];
  int B = in_sizes[0] / (S * S);
  if (B > MAXB) B = MAXB;

  pack_kernel<<<dim3(B * 126), dim3(256), 0, stream>>>(s_sib);
  score_kernel<<<dim3(256), dim3(256), 0, stream>>>(s_arc, s_sib, mask, arcs, sibs, B);
  dp_kernel<0><<<dim3(B), dim3(NT), 0, stream>>>(s_arc, mask);  // real output
  dp_kernel<2><<<dim3(B), dim3(NT), 0, stream>>>(s_arc, mask);  // cl/cr ablation probe
  final_kernel<<<dim3(1), dim3(256), 0, stream>>>(B, (float*)d_out);
}

// Round 18
// 495.467 us; speedup vs baseline: 2.2897x; 2.2897x over previous
//
#include <hip/hip_runtime.h>

#define S 128
#define NEGF (-1e30f)
#define MAXB 16
#define NT 1024
#define STAGE_SZ 8064     // max over wn of 2*(S-wn-1)*((wn-1)|1)  (wn=63)
#define PKB 700000        // per-batch packed sib floats (>= 698250 exact)
#define RL2 1.4426950408889634f   // 1/ln2 : scores -> exp2 domain
#define LN2 0.6931471805599453f

// Native base-2 transcendentals: bare v_exp_f32 / v_log_f32 (both base-2 in HW).
#if __has_builtin(__builtin_amdgcn_exp2f)
#define EXP2(x) __builtin_amdgcn_exp2f(x)
#else
#define EXP2(x) __expf((x) * LN2)
#endif
#if __has_builtin(__builtin_amdgcn_logf)
#define LOG2(x) __builtin_amdgcn_logf(x)
#else
#define LOG2(x) (__logf(x) * RL2)
#endif

// Static device workspace (d_ws proved unreliable in rounds 0-2).
__device__ float g_ssw[MAXB * S * S];        // sibling spans (exp2 domain)
__device__ float g_spk[(size_t)MAXB * PKB];  // packed sib * RL2
__device__ float g_logZ[MAXB];
__device__ float g_partials[512];

__device__ __forceinline__ bool mask_at(const unsigned char* m, int i, bool by) {
  return by ? (m[i] != 0) : (((const int*)m)[i] != 0);
}

// global -> LDS DMA, 4B/lane (r6-r16 verified).
__device__ __forceinline__ void gload_lds4(const float* g, float* l) {
  __builtin_amdgcn_global_load_lds(
      (const __attribute__((address_space(1))) unsigned int*)g,
      (__attribute__((address_space(3))) unsigned int*)l, 4, 0, 0);
}

// Online-lse pieces, exp2 domain (inputs pre-scaled by 1/ln2). Finite NEGF
// sentinel => no NaN.
__device__ __forceinline__ void upd(float& m, float& s, float v) {
  float mn = fmaxf(m, v);
  s = s * EXP2(m - mn) + EXP2(v - mn);
  m = mn;
}
__device__ __forceinline__ void fold(float& m0, float& s0, float m1, float s1) {
  float mn = fmaxf(m0, m1);
  s0 = s0 * EXP2(m0 - mn) + s1 * EXP2(m1 - mn);
  m0 = mn;
}
template <int CTRL>
__device__ __forceinline__ float dpp_f(float x) {
  int i = __float_as_int(x);
  return __int_as_float(__builtin_amdgcn_update_dpp(i, i, CTRL, 0xF, 0xF, false));
}
// Cross-lane (m,s) fold over p=2^lp lane-aligned groups (r5-r16 verified).
__device__ __forceinline__ void xfold(float& m, float& s, int lp) {
  if (lp >= 1) { float mo = dpp_f<0xB1>(m),  so = dpp_f<0xB1>(s);  fold(m, s, mo, so); }
  if (lp >= 2) { float mo = dpp_f<0x4E>(m),  so = dpp_f<0x4E>(s);  fold(m, s, mo, so); }
  if (lp >= 3) { float mo = dpp_f<0x141>(m), so = dpp_f<0x141>(s); fold(m, s, mo, so); }
  if (lp >= 4) { float mo = dpp_f<0x140>(m), so = dpp_f<0x140>(s); fold(m, s, mo, so); }
}
// Division-free lane-split selectors (equiv. to lp_cap(512/nk), lp_cap(256/nk)):
__device__ __forceinline__ int lpA_of(int nk) {        // 512-thread family
  return (nk <= 32) ? 4 : (nk <= 64) ? 3 : 2;
}
__device__ __forceinline__ int lpB_of(int nk) {        // 256-thread family
  return (nk <= 16) ? 4 : (nk <= 32) ? 3 : (nk <= 64) ? 2 : 1;
}

// Chunk-8 accumulate, compile-time strides, exp2 domain (r12-r16 math shape).
template <int SA, int SB>
__device__ __forceinline__ void acc2(const float* a, const float* b,
                                     int n, float& M, float& Ss) {
  int i = 0;
  for (; i + 8 <= n; i += 8) {
    float v0 = a[0 * SA] + b[0 * SB];
    float v1 = a[1 * SA] + b[1 * SB];
    float v2 = a[2 * SA] + b[2 * SB];
    float v3 = a[3 * SA] + b[3 * SB];
    float v4 = a[4 * SA] + b[4 * SB];
    float v5 = a[5 * SA] + b[5 * SB];
    float v6 = a[6 * SA] + b[6 * SB];
    float v7 = a[7 * SA] + b[7 * SB];
    float mc = fmaxf(fmaxf(fmaxf(v0, v1), fmaxf(v2, v3)),
                     fmaxf(fmaxf(v4, v5), fmaxf(v6, v7)));
    float s8 = ((EXP2(v0 - mc) + EXP2(v1 - mc)) +
                (EXP2(v2 - mc) + EXP2(v3 - mc))) +
               ((EXP2(v4 - mc) + EXP2(v5 - mc)) +
                (EXP2(v6 - mc) + EXP2(v7 - mc)));
    float mn = fmaxf(M, mc);
    Ss = Ss * EXP2(M - mn) + s8 * EXP2(mc - mn);
    M = mn;
    a += 8 * SA; b += 8 * SB;
  }
  for (; i < n; ++i) { upd(M, Ss, a[0] + b[0]); a += SA; b += SB; }
}
// 3-stream variant (partial: si LDS + ssw global + stage LDS).
template <int SA, int SB, int SC_>
__device__ __forceinline__ void acc3(const float* a, const float* b,
                                     const float* c, int n, float& M, float& Ss) {
  int i = 0;
  for (; i + 8 <= n; i += 8) {
    float v0 = a[0 * SA] + b[0 * SB] + c[0 * SC_];
    float v1 = a[1 * SA] + b[1 * SB] + c[1 * SC_];
    float v2 = a[2 * SA] + b[2 * SB] + c[2 * SC_];
    float v3 = a[3 * SA] + b[3 * SB] + c[3 * SC_];
    float v4 = a[4 * SA] + b[4 * SB] + c[4 * SC_];
    float v5 = a[5 * SA] + b[5 * SB] + c[5 * SC_];
    float v6 = a[6 * SA] + b[6 * SB] + c[6 * SC_];
    float v7 = a[7 * SA] + b[7 * SB] + c[7 * SC_];
    float mc = fmaxf(fmaxf(fmaxf(v0, v1), fmaxf(v2, v3)),
                     fmaxf(fmaxf(v4, v5), fmaxf(v6, v7)));
    float s8 = ((EXP2(v0 - mc) + EXP2(v1 - mc)) +
                (EXP2(v2 - mc) + EXP2(v3 - mc))) +
               ((EXP2(v4 - mc) + EXP2(v5 - mc)) +
                (EXP2(v6 - mc) + EXP2(v7 - mc)));
    float mn = fmaxf(M, mc);
    Ss = Ss * EXP2(M - mn) + s8 * EXP2(mc - mn);
    M = mn;
    a += 8 * SA; b += 8 * SB; c += 8 * SC_;
  }
  for (; i < n; ++i) { upd(M, Ss, a[0] + b[0] + c[0]); a += SA; b += SB; c += SC_; }
}

// One-time repack of s_sib (scaled into exp2 domain) into stage layout.
__global__ __launch_bounds__(256) void pack_kernel(const float* __restrict__ sib) {
  const int wn = 2 + (blockIdx.x % 126);
  const int b = blockIdx.x / 126;
  const int nk2 = S - wn;
  const int rows1 = nk2 - 1;
  if (rows1 <= 0) return;
  const int rowlen = wn - 1;
  const int rlP = rowlen | 1;
  int off = 0;
  for (int v = 2; v < wn; ++v) off += 2 * (S - v - 1) * ((v - 1) | 1);
  const float* SBraw = sib + (size_t)b * S * S * S;   // [dep][head][sib]
  float* dst = g_spk + (size_t)b * PKB + off;
  const int lane5 = threadIdx.x & 31;
  const int R = 2 * rows1;
  for (int r = (threadIdx.x >> 5); r < R; r += 8) {
    const int typ = (r >= rows1) ? 1 : 0;
    const int kr = (r - typ * rows1) + 1;
    const int kw2 = kr + wn;
    const size_t srcoff = (typ == 0)
        ? ((size_t)(kw2 * S + kr) * S + (kr + 1))
        : ((size_t)(kr * S + kw2) * S + (kr + 1));
    const float* src = SBraw + srcoff;
    float* d = dst + r * rlP;
    for (int i = lane5; i < rowlen; i += 32) d[i] = src[i] * RL2;
  }
}

// One block (1024 thr) per batch element; r15 schedule (2 barriers/width,
// sibling-lse pipelined across the barrier, LDS-staged sib via DMA),
// exp2-domain native transcendentals, division-free lane splits.
__global__ __launch_bounds__(NT) void dp_kernel(
    const float* __restrict__ arc,          // [B,S,S] s_arc[b,dep,head]
    const unsigned char* __restrict__ mask) // [B,S]
{
  __shared__ float si[S][S];
  __shared__ float sc[S][S];
  __shared__ float stage[STAGE_SZ];
  __shared__ int len_sh, cnt0_sh;

  const int b = blockIdx.x;
  const int tid = threadIdx.x;
  const float* arc_b = arc + (size_t)b * S * S;      // arc_b[dep*S+head]
  const float* spk_b = g_spk + (size_t)b * PKB;
  float* ssw = g_ssw + (size_t)b * S * S;

  if (tid == 0) { len_sh = 0; cnt0_sh = 0; }
  __syncthreads();
  if (tid < S && mask[tid] != 0) atomicAdd(&cnt0_sh, 1);  // byte-interp of row 0
  for (int i = tid; i < S * S; i += NT) {
    (&si[0][0])[i] = NEGF;
    (&sc[0][0])[i] = NEGF;
  }
  __syncthreads();
  const bool bytes = (cnt0_sh >= 64);
  if (tid < S) {
    sc[tid][tid] = 0.0f;               // width-0 complete spans
    if (mask_at(mask, b * S + tid, bytes)) atomicAdd(&len_sh, 1);
  }
  __syncthreads();
  const int len = min(len_sh, S - 1);
  if (tid == 0) g_logZ[b] = 0.0f;      // len==0 fallback

  // Pipeline registers (tid >= 512 only).
  float mP = NEGF, sP = 0.f, arcvP = 0.f;
  if (tid >= 512) {                    // prologue for w=1 finish (lpB(127)=1)
    const int fam = (tid >= 768);
    const int floc = tid & 255;
    const int k = floc >> 1;
    if (k < S - 1)
      arcvP = (fam ? arc_b[k * S + (k + 1)] : arc_b[(k + 1) * S + k]) * RL2;
  }

  int spk_off = 0;

  for (int w = 1; w < S; ++w) {
    const int nk = S - w;
    const int wn = w + 1;

    // ===== issue DMA(w+1): stage(w) was last read in PH_B(w-1) =====
    if (wn < S) {
      const int rows1n = S - wn - 1;
      const int T = 2 * rows1n * ((wn - 1) | 1);
      const float* src = spk_b + spk_off;
      const int wv = tid >> 6, l = tid & 63;
      for (int c = wv; c * 64 < T; c += 16) {
        const int e = c * 64 + l;
        if (e < T) gload_lds4(src + e, &stage[c * 64]);
      }
      spk_off += T;
    }

    // ========== PH_A: slr(w) || finish ir/il(w) ==========
    if (tid < 512) {                   // slr: S(k, k+w), k in [1, nk)
      const int lp = lpA_of(nk);
      const int p = 1 << lp;
      const int q = tid & (p - 1);
      const int k = tid >> lp;
      if (k >= 1 && k < nk) {
        const int kw = k + w;
        const int ch = w >> lp;
        const int i0 = q * ch;
        const int n = ((q == p - 1) ? w : i0 + ch) - i0;
        float M = NEGF, Ss = 0.f;
        acc2<1, 1>(&sc[k][k] + i0, &sc[kw][k + 1] + i0, n, M, Ss);
        xfold(M, Ss, lp);
        if (q == 0) ssw[w * S + k] = LOG2(Ss) + M;
      }
    } else {                           // finish ir/il(w) from (mP, sP)
      const int fam = (tid >= 768);
      const int floc = tid & 255;
      const int lp = lpB_of(nk);       // same lp the partial used for width w
      const int p = 1 << lp;
      const int q = floc & (p - 1);
      const int k = floc >> lp;
      if (k < nk) {
        const int kw = k + w;
        float bm;
        if (fam == 0) bm = sc[k][k] + sc[kw][k + 1];
        else bm = (k == 0) ? 0.0f : (sc[kw][kw] + sc[k][kw - 1]);
        float m = mP, s = sP;
        if (q == 0) fold(m, s, bm, 1.0f);
        xfold(m, s, lp);
        if (q == 0) {
          const float r = LOG2(s) + m + arcvP;
          if (fam == 0) si[k][kw] = r;
          else          si[kw][k] = r;
        }
      }
    }
    __syncthreads();   // B1: si(w)/ssw(w) final; DMA(w+1) landed

    // ========== PH_B: cl || cr || partial-ir(w+1) || partial-il(w+1) ======
    if (tid < 512) {
      const int fam = (tid >= 256);    // 0 = cl, 1 = cr
      const int floc = tid & 255;
      const int lp = lpB_of(nk);
      const int p = 1 << lp;
      const int q = floc & (p - 1);
      const int k = floc >> lp;
      if (k < nk) {
        const int kw = k + w;
        const int ch = w >> lp;
        const int i0 = q * ch;
        const int n = ((q == p - 1) ? w : i0 + ch) - i0;
        float M = NEGF, Ss = 0.f;
        if (fam == 0) {      // cl: C(kw->k) over x: sc[k+x][k]+si[kw][k+x]
          acc2<S, 1>(&sc[k + i0][k], &si[kw][k] + i0, n, M, Ss);
          xfold(M, Ss, lp);
          if (q == 0) sc[kw][k] = LOG2(Ss) + M;
        } else {             // cr: C(k->kw) over y: si[k][k+y]+sc[k+y][kw]
          acc2<1, S>(&si[k][k + 1] + i0, &sc[k + 1 + i0][kw], n, M, Ss);
          xfold(M, Ss, lp);
          if (q == 0) {
            const float r = LOG2(Ss) + M;
            if (k == 0) {
              // single-root kill: C(0->w) survives only at w == len
              if (w == len) g_logZ[b] = r * LN2;   // back to nats
              sc[0][w] = (w == len) ? r : NEGF;
            } else {
              sc[k][kw] = r;
            }
          }
        }
      }
    } else {
      // partial sibling-lse for ir/il(w+1); reads si(<=w), ssw(<=w), stage.
      mP = NEGF; sP = 0.f; arcvP = 0.f;
      if (wn < S) {
        const int fam = (tid >= 768);
        const int floc = tid & 255;
        const int nk2 = S - wn;
        const int lp = lpB_of(nk2);
        const int p = 1 << lp;
        const int q = floc & (p - 1);
        const int k = floc >> lp;
        if (k < nk2) {
          const int kw2 = k + wn;
          // arc prefetch for next phase's finish (latency hidden here)
          arcvP = ((fam == 0) ? arc_b[kw2 * S + k] : arc_b[k * S + kw2]) * RL2;
          if (k >= 1) {
            const int n1n = wn - 1;    // sibling count = w
            const int rlPn = n1n | 1;
            const int ch = n1n >> lp;
            const int i0 = q * ch;
            const int n = ((q == p - 1) ? n1n : i0 + ch) - i0;
            if (fam == 0) {
              // ir(k->kw2): si[k][k+1+i] + SSW[wn-1-i][k+1+i] + stage0[k-1][i]
              acc3<1, 1 - S, 1>(&si[k][k + 1] + i0,
                                ssw + (wn - 1) * S + (k + 1) + i0 * (1 - S),
                                &stage[(k - 1) * rlPn] + i0, n, mP, sP);
            } else {
              // il(kw2->k): si[kw2][k+1+i] + SSW[1+i][k] + stage1[k-1][i]
              acc3<1, S, 1>(&si[kw2][k + 1] + i0,
                            ssw + S + k + i0 * S,
                            &stage[((nk2 - 1) + (k - 1)) * rlPn] + i0, n, mP, sP);
            }
          }
        }
      }
    }
    __syncthreads();   // B2: sc(w) final
  }
}

// Gather score (raw domain): masked arc + positive-sibling scores, mask count.
__global__ __launch_bounds__(256) void score_kernel(
    const float* __restrict__ arc, const float* __restrict__ sib,
    const unsigned char* __restrict__ mask, const int* __restrict__ arcs,
    const int* __restrict__ sibs, int B)
{
  __shared__ bool bytes_sh;
  if (threadIdx.x == 0) {
    int c = 0;
    for (int i = 0; i < S; ++i) c += (mask[i] != 0);
    bytes_sh = (c >= 64);
  }
  __syncthreads();
  const bool bytes = bytes_sh;

  const int total = B * S * S;
  int tid = blockIdx.x * blockDim.x + threadIdx.x;
  float sum = 0.f, cnt = 0.f;
  for (int e = tid; e < total; e += gridDim.x * blockDim.x) {
    int sv = sibs[e];
    if (sv > 0) sum += sib[(size_t)e * S + sv];
    if ((e & (S - 1)) == 0) {
      int bi = e >> 7;
      if (mask_at(mask, bi, bytes)) { sum += arc[(size_t)bi * S + arcs[bi]]; cnt += 1.f; }
    }
  }
  __shared__ float rs[256], rc[256];
  rs[threadIdx.x] = sum; rc[threadIdx.x] = cnt;
  __syncthreads();
  for (int off = 128; off; off >>= 1) {
    if (threadIdx.x < off) {
      rs[threadIdx.x] += rs[threadIdx.x + off];
      rc[threadIdx.x] += rc[threadIdx.x + off];
    }
    __syncthreads();
  }
  if (threadIdx.x == 0) {
    g_partials[blockIdx.x * 2]     = rs[0];
    g_partials[blockIdx.x * 2 + 1] = rc[0];
  }
}

__global__ __launch_bounds__(256) void final_kernel(int B, float* __restrict__ out)
{
  __shared__ float rs[256], rc[256];
  int t = threadIdx.x;
  float v = -g_partials[t * 2];
  float c = g_partials[t * 2 + 1];
  if (t < B) v += g_logZ[t];
  rs[t] = v; rc[t] = c;
  __syncthreads();
  for (int off = 128; off; off >>= 1) {
    if (t < off) { rs[t] += rs[t + off]; rc[t] += rc[t + off]; }
    __syncthreads();
  }
  if (t == 0) out[0] = rs[0] / rc[0];   // (logZ - score) / mask.sum()
}

extern "C" void kernel_launch(void* const* d_in, const int* in_sizes, int n_in,
                              void* d_out, int out_size, void* d_ws, size_t ws_size,
                              hipStream_t stream) {
  const float* s_arc = (const float*)d_in[0];
  const float* s_sib = (const float*)d_in[1];
  const unsigned char* mask = (const unsigned char*)d_in[2];
  const int* arcs = (const int*)d_in[3];
  const int* sibs = (const int*)d_in[4];
  int B = in_sizes[0] / (S * S);
  if (B > MAXB) B = MAXB;

  pack_kernel<<<dim3(B * 126), dim3(256), 0, stream>>>(s_sib);
  score_kernel<<<dim3(256), dim3(256), 0, stream>>>(s_arc, s_sib, mask, arcs, sibs, B);
  dp_kernel<<<dim3(B), dim3(NT), 0, stream>>>(s_arc, mask);
  final_kernel<<<dim3(1), dim3(256), 0, stream>>>(B, (float*)d_out);
}